// Round 3
// baseline (668.225 us; speedup 1.0000x reference)
//
#include <hip/hip_runtime.h>
#include <stdint.h>

#define N 512
#define D 128
#define P (N * N)

typedef float floatx4 __attribute__((ext_vector_type(4)));
typedef _Float16 f16x8 __attribute__((ext_vector_type(8)));

__device__ __forceinline__ unsigned short f2h(float f) {
    _Float16 h = (_Float16)f;  // v_cvt_f16_f32, RNE
    return __builtin_bit_cast(unsigned short, h);
}
__device__ __forceinline__ unsigned int packh(float a, float b) {
    return (unsigned int)f2h(a) | ((unsigned int)f2h(b) << 16);
}
__device__ __forceinline__ float h2f(unsigned short u) {
    return (float)__builtin_bit_cast(_Float16, u);
}
__device__ __forceinline__ float sigm(float x) { return 1.0f / (1.0f + __expf(-x)); }

// fp32 [128][128] row-major global -> fp16 LDS [128][136] (padded: +8 keeps 16B align)
__device__ __forceinline__ void load_w_f16(const float* __restrict__ W,
                                           unsigned short (*sW)[136], int t) {
    const int r = t >> 1, h = t & 1;
    const float4* src = (const float4*)(W + r * 128 + h * 64);
    uint2* dst = (uint2*)&sW[r][h * 64];
#pragma unroll
    for (int i = 0; i < 16; ++i) {
        float4 v = src[i];
        uint2 o;
        o.x = packh(v.x, v.y);
        o.y = packh(v.z, v.w);
        dst[i] = o;
    }
}

// NT MFMA over K=128: A frags preloaded ([kk][mi]), B rows = out-channels in sB.
__device__ __forceinline__ void mfma_tile_pre(const unsigned short (*sB)[136],
                                              const f16x8 (&afrag)[4][4],
                                              int wn, int lm, int quad,
                                              floatx4 (&acc)[4][4]) {
#pragma unroll
    for (int kk = 0; kk < 4; ++kk) {
        f16x8 bf[4];
#pragma unroll
        for (int ni = 0; ni < 4; ++ni)
            bf[ni] = *(const f16x8*)&sB[wn * 64 + ni * 16 + lm][kk * 32 + quad * 8];
#pragma unroll
        for (int mi = 0; mi < 4; ++mi)
#pragma unroll
            for (int ni = 0; ni < 4; ++ni)
                acc[mi][ni] = __builtin_amdgcn_mfma_f32_16x16x32_f16(
                    afrag[kk][mi], bf[ni], acc[mi][ni], 0, 0, 0);
    }
}

__device__ __forceinline__ void zero_acc(floatx4 (&a)[4][4]) {
#pragma unroll
    for (int mi = 0; mi < 4; ++mi)
#pragma unroll
        for (int ni = 0; ni < 4; ++ni) {
            floatx4 z = {0.f, 0.f, 0.f, 0.f};
            a[mi][ni] = z;
        }
}

// ---------------- Kernel 1: LN(pair) + 5 projections + gating ----------------
// left/right stored split hi/lo fp16 (lo pre-scaled by 2048) for fp32-grade einsum.
__global__ __launch_bounds__(256, 2) void k_proj(
    const float* __restrict__ pair, const float* __restrict__ mask,
    const float* __restrict__ nw, const float* __restrict__ nb,
    const float* __restrict__ lpw, const float* __restrict__ lpb,
    const float* __restrict__ lgw, const float* __restrict__ lgb,
    const float* __restrict__ rpw, const float* __restrict__ rpb,
    const float* __restrict__ rgw, const float* __restrict__ rgb,
    const float* __restrict__ ogw, const float* __restrict__ ogb,
    unsigned short* __restrict__ LhiT, unsigned short* __restrict__ LloT,
    unsigned short* __restrict__ RhiT, unsigned short* __restrict__ RloT,
    unsigned short* __restrict__ gate) {
    __shared__ __align__(16) unsigned short sA[128][136];
    __shared__ __align__(16) unsigned short sW[128][136];  // weights, then transpose buffer
    __shared__ float sPar[7][128];                         // nw nb lpb lgb rpb rgb ogb
    __shared__ float sMask[128];

    const int t = threadIdx.x;
    const size_t px0 = (size_t)blockIdx.x * 128;

    if (t < 128) {
        sPar[0][t] = nw[t];  sPar[1][t] = nb[t];
        sPar[2][t] = lpb[t]; sPar[3][t] = lgb[t];
        sPar[4][t] = rpb[t]; sPar[5][t] = rgb[t];
        sPar[6][t] = ogb[t];
        sMask[t] = mask[px0 + t];
    }

    // --- LayerNorm of 128-pixel tile -> fp16 in sA[px][d] ---
    {
        const int pxl = t >> 1, h = t & 1;  // 2 threads per pixel, 64 ch each
        const float4* src = (const float4*)(pair + (px0 + pxl) * 128 + h * 64);
        float4 v[16];
        float s = 0.f, sq = 0.f;
#pragma unroll
        for (int i = 0; i < 16; ++i) {
            v[i] = src[i];
            s += v[i].x + v[i].y + v[i].z + v[i].w;
            sq += v[i].x * v[i].x + v[i].y * v[i].y + v[i].z * v[i].z + v[i].w * v[i].w;
        }
        s += __shfl_xor(s, 1);
        sq += __shfl_xor(sq, 1);
        const float mean = s * (1.f / 128.f);
        const float var = sq * (1.f / 128.f) - mean * mean;
        const float rstd = rsqrtf(var + 1e-5f);
        __syncthreads();  // sPar ready
        uint2* dst = (uint2*)&sA[pxl][h * 64];
#pragma unroll
        for (int i = 0; i < 16; ++i) {
            const int c = h * 64 + i * 4;
            float a0 = (v[i].x - mean) * rstd * sPar[0][c + 0] + sPar[1][c + 0];
            float a1 = (v[i].y - mean) * rstd * sPar[0][c + 1] + sPar[1][c + 1];
            float a2 = (v[i].z - mean) * rstd * sPar[0][c + 2] + sPar[1][c + 2];
            float a3 = (v[i].w - mean) * rstd * sPar[0][c + 3] + sPar[1][c + 3];
            uint2 o;
            o.x = packh(a0, a1);
            o.y = packh(a2, a3);
            dst[i] = o;
        }
    }
    __syncthreads();

    const int wave = t >> 6, lane = t & 63, quad = lane >> 4, lm = lane & 15;
    const int wm = wave >> 1, wn = wave & 1;

    // preload A fragments once (shared across all 5 GEMMs)
    f16x8 afrag[4][4];
#pragma unroll
    for (int kk = 0; kk < 4; ++kk)
#pragma unroll
        for (int mi = 0; mi < 4; ++mi)
            afrag[kk][mi] = *(const f16x8*)&sA[wm * 64 + mi * 16 + lm][kk * 32 + quad * 8];

    floatx4 accP[4][4], accG[4][4];

#pragma unroll 1
    for (int side = 0; side < 2; ++side) {
        const float* Wp = side ? rpw : lpw;
        const float* Wg = side ? rgw : lgw;
        const int bP = side ? 4 : 2, bG = side ? 5 : 3;
        unsigned short* hiT = side ? RhiT : LhiT;
        unsigned short* loT = side ? RloT : LloT;

        load_w_f16(Wp, sW, t);
        __syncthreads();
        zero_acc(accP);
        mfma_tile_pre(sW, afrag, wn, lm, quad, accP);
        __syncthreads();

        load_w_f16(Wg, sW, t);
        __syncthreads();
        zero_acc(accG);
        mfma_tile_pre(sW, afrag, wn, lm, quad, accG);

        // in-place: accP <- left = (proj+b)*sigmoid(gate+b)*mask (fp32)
#pragma unroll
        for (int mi = 0; mi < 4; ++mi) {
            const int rowb = wm * 64 + mi * 16 + quad * 4;
#pragma unroll
            for (int ni = 0; ni < 4; ++ni) {
                const int col = wn * 64 + ni * 16 + lm;
                const float biasP = sPar[bP][col], biasG = sPar[bG][col];
#pragma unroll
                for (int rr = 0; rr < 4; ++rr)
                    accP[mi][ni][rr] = (accP[mi][ni][rr] + biasP) *
                                       sigm(accG[mi][ni][rr] + biasG) * sMask[rowb + rr];
            }
        }
        __syncthreads();  // all waves done reading sW (Wg)

        // pass 1: hi halves, transposed into sW[col(d)][row(px)]
#pragma unroll
        for (int mi = 0; mi < 4; ++mi) {
            const int rowb = wm * 64 + mi * 16 + quad * 4;
#pragma unroll
            for (int ni = 0; ni < 4; ++ni) {
                const int col = wn * 64 + ni * 16 + lm;
                *(unsigned int*)&sW[col][rowb] = packh(accP[mi][ni][0], accP[mi][ni][1]);
                *(unsigned int*)&sW[col][rowb + 2] = packh(accP[mi][ni][2], accP[mi][ni][3]);
            }
        }
        __syncthreads();
        {
            const int dch = t >> 1, h = t & 1;
            const uint4* srcp = (const uint4*)&sW[dch][h * 64];
            uint4* dstp = (uint4*)(hiT + (size_t)dch * P + px0 + h * 64);
#pragma unroll
            for (int i = 0; i < 8; ++i) dstp[i] = srcp[i];
        }
        __syncthreads();

        // pass 2: lo halves (residual * 2048), transposed
#pragma unroll
        for (int mi = 0; mi < 4; ++mi) {
            const int rowb = wm * 64 + mi * 16 + quad * 4;
#pragma unroll
            for (int ni = 0; ni < 4; ++ni) {
                const int col = wn * 64 + ni * 16 + lm;
                float l0 = accP[mi][ni][0], l1 = accP[mi][ni][1];
                float l2 = accP[mi][ni][2], l3 = accP[mi][ni][3];
                float lo0 = (l0 - h2f(f2h(l0))) * 2048.f;
                float lo1 = (l1 - h2f(f2h(l1))) * 2048.f;
                float lo2 = (l2 - h2f(f2h(l2))) * 2048.f;
                float lo3 = (l3 - h2f(f2h(l3))) * 2048.f;
                *(unsigned int*)&sW[col][rowb] = packh(lo0, lo1);
                *(unsigned int*)&sW[col][rowb + 2] = packh(lo2, lo3);
            }
        }
        __syncthreads();
        {
            const int dch = t >> 1, h = t & 1;
            const uint4* srcp = (const uint4*)&sW[dch][h * 64];
            uint4* dstp = (uint4*)(loT + (size_t)dch * P + px0 + h * 64);
#pragma unroll
            for (int i = 0; i < 8; ++i) dstp[i] = srcp[i];
        }
        __syncthreads();
    }

    // --- output gate: sigmoid(p@ogw.T + ogb), natural [px][d] layout ---
    load_w_f16(ogw, sW, t);
    __syncthreads();
    zero_acc(accG);
    mfma_tile_pre(sW, afrag, wn, lm, quad, accG);
#pragma unroll
    for (int mi = 0; mi < 4; ++mi) {
        const int rowb = wm * 64 + mi * 16 + quad * 4;
#pragma unroll
        for (int ni = 0; ni < 4; ++ni) {
            const int col = wn * 64 + ni * 16 + lm;
            const float biasG = sPar[6][col];
#pragma unroll
            for (int rr = 0; rr < 4; ++rr)
                gate[(px0 + rowb + rr) * 128 + col] = f2h(sigm(accG[mi][ni][rr] + biasG));
        }
    }
}

// ---------------- Kernel 2: batched NT GEMM  E_d = L_d @ R_d^T (split-fp16) ----------------
// E = hh + 2^-11*(h*lo + lo*h); drops lo*lo (~2^-22 rel) -> fp32-grade einsum.
__global__ __launch_bounds__(256, 2) void k_einsum(
    const unsigned short* __restrict__ Lhi, const unsigned short* __restrict__ Llo,
    const unsigned short* __restrict__ Rhi, const unsigned short* __restrict__ Rlo,
    unsigned short* __restrict__ E) {
    __shared__ __align__(16) unsigned short sAh[128 * 32];
    __shared__ __align__(16) unsigned short sAl[128 * 32];
    __shared__ __align__(16) unsigned short sBh[128 * 32];
    __shared__ __align__(16) unsigned short sBl[128 * 32];

    const int t = threadIdx.x;
    const int d = blockIdx.y;
    const int i0 = (blockIdx.x >> 2) * 128;
    const int j0 = (blockIdx.x & 3) * 128;
    const unsigned short* Ah = Lhi + (size_t)d * P;
    const unsigned short* Al = Llo + (size_t)d * P;
    const unsigned short* Bh = Rhi + (size_t)d * P;
    const unsigned short* Bl = Rlo + (size_t)d * P;

    const int wave = t >> 6, lane = t & 63, quad = lane >> 4, lm = lane & 15;
    const int wm = wave >> 1, wn = wave & 1;

    floatx4 acc[4][4], acc2[4][4];
    zero_acc(acc);
    zero_acc(acc2);

    const int r0 = t >> 2, ko0 = (t & 3) * 8;
    const int r1 = (t + 256) >> 2, ko1 = ((t + 256) & 3) * 8;
    const size_t oa0 = (size_t)(i0 + r0) * 512 + ko0;
    const size_t oa1 = (size_t)(i0 + r1) * 512 + ko1;
    const size_t ob0 = (size_t)(j0 + r0) * 512 + ko0;
    const size_t ob1 = (size_t)(j0 + r1) * 512 + ko1;

    uint4 pah0 = *(const uint4*)(Ah + oa0), pal0 = *(const uint4*)(Al + oa0);
    uint4 pbh0 = *(const uint4*)(Bh + ob0), pbl0 = *(const uint4*)(Bl + ob0);
    uint4 pah1 = *(const uint4*)(Ah + oa1), pal1 = *(const uint4*)(Al + oa1);
    uint4 pbh1 = *(const uint4*)(Bh + ob1), pbl1 = *(const uint4*)(Bl + ob1);

    for (int kt = 0; kt < 16; ++kt) {
        __syncthreads();  // all waves done reading previous LDS tile
        *(uint4*)&sAh[t * 8] = pah0;
        *(uint4*)&sAl[t * 8] = pal0;
        *(uint4*)&sBh[t * 8] = pbh0;
        *(uint4*)&sBl[t * 8] = pbl0;
        *(uint4*)&sAh[(t + 256) * 8] = pah1;
        *(uint4*)&sAl[(t + 256) * 8] = pal1;
        *(uint4*)&sBh[(t + 256) * 8] = pbh1;
        *(uint4*)&sBl[(t + 256) * 8] = pbl1;
        __syncthreads();
        if (kt < 15) {  // prefetch next tile; overlaps with MFMA below
            const int k0 = (kt + 1) * 32;
            pah0 = *(const uint4*)(Ah + oa0 + k0);
            pal0 = *(const uint4*)(Al + oa0 + k0);
            pbh0 = *(const uint4*)(Bh + ob0 + k0);
            pbl0 = *(const uint4*)(Bl + ob0 + k0);
            pah1 = *(const uint4*)(Ah + oa1 + k0);
            pal1 = *(const uint4*)(Al + oa1 + k0);
            pbh1 = *(const uint4*)(Bh + ob1 + k0);
            pbl1 = *(const uint4*)(Bl + ob1 + k0);
        }
        f16x8 afh[4], afl[4], bfh[4], bfl[4];
#pragma unroll
        for (int mi = 0; mi < 4; ++mi) {
            const int ro = (wm * 64 + mi * 16 + lm) * 32 + quad * 8;
            afh[mi] = *(const f16x8*)&sAh[ro];
            afl[mi] = *(const f16x8*)&sAl[ro];
        }
#pragma unroll
        for (int ni = 0; ni < 4; ++ni) {
            const int ro = (wn * 64 + ni * 16 + lm) * 32 + quad * 8;
            bfh[ni] = *(const f16x8*)&sBh[ro];
            bfl[ni] = *(const f16x8*)&sBl[ro];
        }
#pragma unroll
        for (int mi = 0; mi < 4; ++mi)
#pragma unroll
            for (int ni = 0; ni < 4; ++ni) {
                acc[mi][ni] =
                    __builtin_amdgcn_mfma_f32_16x16x32_f16(afh[mi], bfh[ni], acc[mi][ni], 0, 0, 0);
                acc2[mi][ni] =
                    __builtin_amdgcn_mfma_f32_16x16x32_f16(afh[mi], bfl[ni], acc2[mi][ni], 0, 0, 0);
                acc2[mi][ni] =
                    __builtin_amdgcn_mfma_f32_16x16x32_f16(afl[mi], bfh[ni], acc2[mi][ni], 0, 0, 0);
            }
    }

    unsigned short* Cd = E + (size_t)d * P;
#pragma unroll
    for (int mi = 0; mi < 4; ++mi) {
        const int rowb = i0 + wm * 64 + mi * 16 + quad * 4;
#pragma unroll
        for (int ni = 0; ni < 4; ++ni) {
            const int col = j0 + wn * 64 + ni * 16 + lm;
#pragma unroll
            for (int rr = 0; rr < 4; ++rr) {
                float e = acc[mi][ni][rr] + acc2[mi][ni][rr] * (1.0f / 2048.0f);
                Cd[(size_t)(rowb + rr) * 512 + col] = f2h(e);
            }
        }
    }
}

// ---------------- Kernel 3: LN(einsum) @ opw.T + opb, * gate ----------------
__global__ __launch_bounds__(256, 2) void k_final(const unsigned short* __restrict__ E,
                                                  const unsigned short* __restrict__ G,
                                                  const float* __restrict__ onw,
                                                  const float* __restrict__ onb,
                                                  const float* __restrict__ opw,
                                                  const float* __restrict__ opb,
                                                  float* __restrict__ out) {
    __shared__ __align__(16) unsigned short sA[128][136];
    __shared__ __align__(16) unsigned short sW[128][136];
    __shared__ float sP[3][128];  // onw onb opb

    const int t = threadIdx.x;
    const size_t px0 = (size_t)blockIdx.x * 128;

    if (t < 128) {
        sP[0][t] = onw[t];
        sP[1][t] = onb[t];
        sP[2][t] = opb[t];
    }
    load_w_f16(opw, sW, t);

    const int wave = t >> 6, lane = t & 63, quad = lane >> 4, lm = lane & 15;
    const int px = wave * 32 + (lane & 31);  // pixel within tile, 2 threads/pixel
    const int h2 = lane >> 5;                // which 64-channel half

    float x[64];
    float s = 0.f, sq = 0.f;
#pragma unroll
    for (int dd = 0; dd < 64; ++dd) {
        const int dch = h2 * 64 + dd;
        const float v = h2f(E[(size_t)dch * P + px0 + px]);
        x[dd] = v;
        s += v;
        sq += v * v;
    }
    s += __shfl_xor(s, 32);
    sq += __shfl_xor(sq, 32);
    const float mean = s * (1.f / 128.f);
    const float var = sq * (1.f / 128.f) - mean * mean;
    const float rstd = rsqrtf(var + 1e-5f);
    __syncthreads();  // sP + sW visible
#pragma unroll
    for (int dd = 0; dd < 64; dd += 2) {
        const int dch = h2 * 64 + dd;
        float a0 = (x[dd] - mean) * rstd * sP[0][dch] + sP[1][dch];
        float a1 = (x[dd + 1] - mean) * rstd * sP[0][dch + 1] + sP[1][dch + 1];
        *(unsigned int*)&sA[px][dch] = packh(a0, a1);
    }
    __syncthreads();

    const int wm = wave >> 1, wn = wave & 1;
    f16x8 afrag[4][4];
#pragma unroll
    for (int kk = 0; kk < 4; ++kk)
#pragma unroll
        for (int mi = 0; mi < 4; ++mi)
            afrag[kk][mi] = *(const f16x8*)&sA[wm * 64 + mi * 16 + lm][kk * 32 + quad * 8];

    floatx4 acc[4][4];
    zero_acc(acc);
    mfma_tile_pre(sW, afrag, wn, lm, quad, acc);

#pragma unroll
    for (int mi = 0; mi < 4; ++mi) {
        const int rowb = wm * 64 + mi * 16 + quad * 4;
#pragma unroll
        for (int ni = 0; ni < 4; ++ni) {
            const int col = wn * 64 + ni * 16 + lm;
            const float bias = sP[2][col];
#pragma unroll
            for (int rr = 0; rr < 4; ++rr) {
                const size_t pix = px0 + rowb + rr;
                const float g = h2f(G[pix * 128 + col]);
                out[pix * 128 + col] = (acc[mi][ni][rr] + bias) * g;
            }
        }
    }
}

extern "C" void kernel_launch(void* const* d_in, const int* in_sizes, int n_in, void* d_out,
                              int out_size, void* d_ws, size_t ws_size, hipStream_t stream) {
    const float* pair = (const float*)d_in[0];
    const float* mask = (const float*)d_in[1];
    const float* nw   = (const float*)d_in[2];
    const float* nb   = (const float*)d_in[3];
    const float* lpw  = (const float*)d_in[4];
    const float* lpb  = (const float*)d_in[5];
    const float* lgw  = (const float*)d_in[6];
    const float* lgb  = (const float*)d_in[7];
    const float* rpw  = (const float*)d_in[8];
    const float* rpb  = (const float*)d_in[9];
    const float* rgw  = (const float*)d_in[10];
    const float* rgb  = (const float*)d_in[11];
    const float* onw  = (const float*)d_in[12];
    const float* onb  = (const float*)d_in[13];
    const float* opw  = (const float*)d_in[14];
    const float* opb  = (const float*)d_in[15];
    const float* ogw  = (const float*)d_in[16];
    const float* ogb  = (const float*)d_in[17];

    unsigned short* LhiT  = (unsigned short*)d_ws;        // [D][P] f16
    unsigned short* LloT  = LhiT + (size_t)P * D;
    unsigned short* RhiT  = LloT + (size_t)P * D;
    unsigned short* RloT  = RhiT + (size_t)P * D;
    unsigned short* gateB = RloT + (size_t)P * D;         // [P][D] f16
    unsigned short* einB  = gateB + (size_t)P * D;        // [D][P] f16

    k_proj<<<P / 128, 256, 0, stream>>>(pair, mask, nw, nb, lpw, lpb, lgw, lgb, rpw, rpb, rgw,
                                        rgb, ogw, ogb, LhiT, LloT, RhiT, RloT, gateB);
    k_einsum<<<dim3(16, 128), 256, 0, stream>>>(LhiT, LloT, RhiT, RloT, einB);
    k_final<<<P / 128, 256, 0, stream>>>(einB, gateB, onw, onb, opw, opb, (float*)d_out);
}